// Round 1
// 685.461 us; speedup vs baseline: 1.1144x; 1.1144x over previous
//
#include <hip/hip_runtime.h>
#include <hip/hip_bf16.h>

#define BB 64
#define TT 1536
#define FF 512
#define TP 256
#define UU 256
#define GG 1024
#define NC 250

typedef _Float16 h2_t __attribute__((ext_vector_type(2)));
typedef _Float16 f16x8 __attribute__((ext_vector_type(8)));
typedef float f32x4 __attribute__((ext_vector_type(4)));

#if defined(__has_builtin)
#  if __has_builtin(__builtin_amdgcn_fdot2)
#    define FDOT2(a, b, c) __builtin_amdgcn_fdot2((a), (b), (c), false)
#  endif
#endif
#ifndef FDOT2
__device__ __forceinline__ float fdot2_fb(h2_t a, h2_t b, float c) {
    return c + (float)a[0] * (float)b[0] + (float)a[1] * (float)b[1];
}
#  define FDOT2(a, b, c) fdot2_fb((a), (b), (c))
#endif

#define BC(u) __builtin_bit_cast(h2_t, (u))

__device__ __forceinline__ float hsig(float z) {
    return fminf(fmaxf(fmaf(z, 0.2f, 0.5f), 0.0f), 1.0f);
}

__device__ __forceinline__ float ftanh(float x) {
    float ax = fabsf(x);
    float e = __expf(-2.0f * ax);
    float t = (1.0f - e) / (1.0f + e);
    return copysignf(t, x);
}

__device__ __forceinline__ void dot4(float& z, const uint4& r, const uint4& h) {
    z = FDOT2(BC(r.x), BC(h.x), z);
    z = FDOT2(BC(r.y), BC(h.y), z);
    z = FDOT2(BC(r.z), BC(h.z), z);
    z = FDOT2(BC(r.w), BC(h.w), z);
}

// pair swap via DPP quad_perm [1,0,3,2] (VALU pipe, no LDS)
#if defined(__has_builtin) && __has_builtin(__builtin_amdgcn_mov_dpp)
template <int CTRL>
__device__ __forceinline__ float qperm(float v) {
    return __builtin_bit_cast(float,
        __builtin_amdgcn_mov_dpp(__builtin_bit_cast(int, v), CTRL, 0xf, 0xf, true));
}
#else
template <int CTRL>
__device__ __forceinline__ float qperm(float v) {
    return __shfl_xor(v, CTRL == 0xB1 ? 1 : 2, 64);
}
#endif

// ---------------------------------------------------------------------------
// Kernel 1: AveragePooling1D(6). x[64,1536,512] f32 -> xph[64,256,512] f16.
// float4 per thread (4 outputs), fully coalesced.
// ---------------------------------------------------------------------------
__global__ __launch_bounds__(256) void pool_kernel(const float* __restrict__ x,
                                                   _Float16* __restrict__ xph) {
    int idx = blockIdx.x * 256 + threadIdx.x;   // [0, 2097152)
    int f4 = (idx & 127) << 2;
    int m = idx >> 7;                           // b*256 + tp
    int tp = m & (TP - 1);
    int b = m >> 8;
    const float* src = x + ((size_t)b * TT + (size_t)tp * 6) * FF + f4;
    float sx = 0.f, sy = 0.f, sz = 0.f, sw = 0.f;
#pragma unroll
    for (int j = 0; j < 6; ++j) {
        float4 v = *(const float4*)&src[j * FF];
        sx += v.x; sy += v.y; sz += v.z; sw += v.w;
    }
    const float r6 = 1.0f / 6.0f;
    h2_t lo, hi;
    lo[0] = (_Float16)(sx * r6); lo[1] = (_Float16)(sy * r6);
    hi[0] = (_Float16)(sz * r6); hi[1] = (_Float16)(sw * r6);
    float2 w = make_float2(__builtin_bit_cast(float, lo), __builtin_bit_cast(float, hi));
    *(float2*)&xph[(size_t)m * FF + f4] = w;
}

// ---------------------------------------------------------------------------
// Kernel 2: tiled transpose + f32->f16 convert. in f32 [K][N] -> out f16 [N][K].
// PERM=1 additionally permutes out row: n=(g*256+u) -> u*4+g (gate-major -> unit-major),
// so the GEMM writes zx directly in float4-per-unit order. Coalesced both sides.
// ---------------------------------------------------------------------------
template <int PERM>
__global__ __launch_bounds__(256) void transpose_cvt(const float* __restrict__ in,
                                                     _Float16* __restrict__ out,
                                                     int K, int N) {
    __shared__ _Float16 tile[32][42];   // pad 42 -> conflict-light transpose reads
    const int r = threadIdx.x >> 3;          // 0..31
    const int c4 = (threadIdx.x & 7) << 2;   // 0,4,..,28
    const int n0 = blockIdx.x << 5;
    const int k0 = blockIdx.y << 5;
    float4 v = *(const float4*)&in[(size_t)(k0 + r) * N + n0 + c4];
    tile[r][c4 + 0] = (_Float16)v.x;
    tile[r][c4 + 1] = (_Float16)v.y;
    tile[r][c4 + 2] = (_Float16)v.z;
    tile[r][c4 + 3] = (_Float16)v.w;
    __syncthreads();
    int n = n0 + r;
    int orow = PERM ? (((n & 255) << 2) | (n >> 8)) : n;
    h2_t lo, hi;
    lo[0] = tile[c4 + 0][r]; lo[1] = tile[c4 + 1][r];
    hi[0] = tile[c4 + 2][r]; hi[1] = tile[c4 + 3][r];
    float2 w = make_float2(__builtin_bit_cast(float, lo), __builtin_bit_cast(float, hi));
    *(float2*)&out[(size_t)orow * K + k0 + c4] = w;
}

// ---------------------------------------------------------------------------
// Kernel 3: zx = xph @ W + b via f16 MFMA 16x16x32. M=16384,N=1024,K=512.
// B columns are permuted (unit-major, col' = u*4+g) via Wtp; bias index un-permuted.
// ---------------------------------------------------------------------------
__global__ __launch_bounds__(256, 2) void gemm_zx_mfma(const _Float16* __restrict__ Ah,
                                                       const _Float16* __restrict__ Bt,
                                                       const float* __restrict__ bias,
                                                       float* __restrict__ C) {
    __shared__ _Float16 As[128 * 40];   // row stride 40 f16 (pad) = 80 B
    __shared__ _Float16 Bs[128 * 40];
    const int tid = threadIdx.x;
    const int bn = blockIdx.x * 128;
    const int bm = blockIdx.y * 128;
    const int wave = tid >> 6, lane = tid & 63;
    const int wm = (wave & 1) * 64, wn = (wave >> 1) * 64;
    const int l15 = lane & 15, q8 = (lane >> 4) * 8;
    const int srow = tid >> 1, shalf = tid & 1;

    f32x4 acc[4][4] = {};
    const uint4* ag = (const uint4*)(Ah + (size_t)(bm + srow) * FF);
    const uint4* bg = (const uint4*)(Bt + (size_t)(bn + srow) * FF);
    uint4* as_st = (uint4*)As + 5 * srow + 2 * shalf;
    uint4* bs_st = (uint4*)Bs + 5 * srow + 2 * shalf;

    for (int k0 = 0; k0 < FF; k0 += 32) {
        int qi = (k0 >> 3) + shalf * 2;
        uint4 a0 = ag[qi], a1 = ag[qi + 1];
        uint4 b0 = bg[qi], b1 = bg[qi + 1];
        __syncthreads();
        as_st[0] = a0; as_st[1] = a1;
        bs_st[0] = b0; bs_st[1] = b1;
        __syncthreads();
        f16x8 af[4], bf[4];
#pragma unroll
        for (int mt = 0; mt < 4; ++mt)
            af[mt] = *(const f16x8*)&As[(wm + 16 * mt + l15) * 40 + q8];
#pragma unroll
        for (int nt = 0; nt < 4; ++nt)
            bf[nt] = *(const f16x8*)&Bs[(wn + 16 * nt + l15) * 40 + q8];
#pragma unroll
        for (int mt = 0; mt < 4; ++mt)
#pragma unroll
            for (int nt = 0; nt < 4; ++nt)
                acc[mt][nt] = __builtin_amdgcn_mfma_f32_16x16x32_f16(af[mt], bf[nt],
                                                                    acc[mt][nt], 0, 0, 0);
    }
    const int rq = (lane >> 4) * 4;
#pragma unroll
    for (int nt = 0; nt < 4; ++nt) {
        int col = bn + wn + 16 * nt + l15;            // permuted col' = u*4+g
        int oc = ((col & 3) << 8) | (col >> 2);       // original col = g*256+u
        float bv = bias[oc];
#pragma unroll
        for (int mt = 0; mt < 4; ++mt) {
#pragma unroll
            for (int r = 0; r < 4; ++r) {
                int row = bm + wm + 16 * mt + rq + r;
                C[(size_t)row * GG + col] = ((const float*)&acc[mt][nt])[r] + bv;
            }
        }
    }
}

// ---------------------------------------------------------------------------
// Kernel 4: LSTM scan. 64 WGs (one per batch), 512 threads.
// Gate-major ownership: thread t -> unit u=t>>1 (all 4 gates), K-half s=t&1.
// R quads (8 f16 of one Rt row each): 46 in VGPRs + 14 in LDS + 4 streamed
// (32 KB window -> L1-resident). One DPP pair-swap reduces K; all 4 gate z's
// land in the owning lane -> gates computed redundantly by the pair (wave-dense,
// bit-identical), no zfull round-trip, ONE barrier/step via double-buffered h.
// zx read as one float4/thread/step (prefetched one step ahead).
// ---------------------------------------------------------------------------
__global__ __launch_bounds__(512, 2) void lstm_scan(const float* __restrict__ zx,
                                                    const _Float16* __restrict__ Rt,
                                                    float* __restrict__ hfin) {
    __shared__ uint4 Rl[14][512];                    // 114688 B
    __shared__ __align__(16) _Float16 hbuf[2][UU];   // 1024 B, double-buffered
    const int b = blockIdx.x;
    const int t = threadIdx.x;
    const int u = t >> 1, s = t & 1;

    // Rt row (g*256+u) = 32 uint4; quad (g,kk) covers k = 128*s + 8*kk .. +7
    const uint4* rt = (const uint4*)Rt + (size_t)u * 32 + (s << 4);

    uint4 rv[46];
    // placement: g0,g1: kk 0..11 reg / 12..14 LDS; g2,g3: kk 0..10 reg / 11..14 LDS; kk15 streamed
#pragma unroll
    for (int g = 0; g < 4; ++g) {
        const int RC = (g < 2) ? 12 : 11;
        const int RO = (g == 0) ? 0 : (g == 1) ? 12 : (g == 2) ? 24 : 35;
        const int LO = (g == 0) ? 0 : (g == 1) ? 3 : (g == 2) ? 6 : 10;
#pragma unroll
        for (int kk = 0; kk < 15; ++kk) {
            if (kk < RC) rv[RO + kk] = rt[g * 8192 + kk];
            else         Rl[LO + kk - RC][t] = rt[g * 8192 + kk];
        }
    }
    if (t < 256) ((unsigned*)hbuf)[t] = 0u;   // zero both h buffers (1 KB)
    float c = 0.0f;
    const float4* zxp = (const float4*)zx + (size_t)b * TP * UU + u;  // +UU per step
    float4 zn = zxp[0];
    __syncthreads();

#pragma unroll 1
    for (int step = 0; step < TP; ++step) {
        // prefetch next step's zx (covers HBM/L3 latency under this step's dots)
        float4 zn2 = zxp[(size_t)((step + 1 < TP) ? step + 1 : step) * UU];
        uint4 st[4];
#pragma unroll
        for (int g = 0; g < 4; ++g) st[g] = rt[g * 8192 + 15];   // L1-hot after step 0

        const uint4* hq = (const uint4*)hbuf[step & 1] + (s << 4);
        float z[4] = {0.f, 0.f, 0.f, 0.f};
#pragma unroll
        for (int kk = 0; kk < 16; ++kk) {
            uint4 hh = hq[kk];   // 2-address broadcast read (conflict-free)
#pragma unroll
            for (int g = 0; g < 4; ++g) {
                const int RC = (g < 2) ? 12 : 11;
                const int RO = (g == 0) ? 0 : (g == 1) ? 12 : (g == 2) ? 24 : 35;
                const int LO = (g == 0) ? 0 : (g == 1) ? 3 : (g == 2) ? 6 : 10;
                if (kk < RC)      dot4(z[g], rv[RO + kk], hh);
                else if (kk < 15) dot4(z[g], Rl[LO + kk - RC][t], hh);
                else              dot4(z[g], st[g], hh);
            }
        }
        // single pair-swap completes the K reduction; both lanes get full sums
#pragma unroll
        for (int g = 0; g < 4; ++g) z[g] += qperm<0xB1>(z[g]);

        float ig = hsig(z[0] + zn.x);
        float fg = hsig(z[1] + zn.y);
        float gv = ftanh(z[2] + zn.z);
        float og = hsig(z[3] + zn.w);
        c = fmaf(fg, c, ig * gv);
        float h = og * ftanh(c);
        if (s == 0) {
            hbuf[(step + 1) & 1][u] = (_Float16)h;
            if (step == TP - 1) hfin[(size_t)b * UU + u] = h;
        }
        zn = zn2;
        __syncthreads();   // one barrier per step (write buf != read buf)
    }
}

// ---------------------------------------------------------------------------
// Kernel 5: logits = h @ Wd + bd; softmax. One WG per batch row.
// ---------------------------------------------------------------------------
__global__ __launch_bounds__(256) void dense_softmax(const float* __restrict__ hfin,
                                                     const float* __restrict__ Wd,
                                                     const float* __restrict__ bd,
                                                     float* __restrict__ out) {
    __shared__ __align__(16) float hbuf[UU];
    __shared__ float red[256];
    const int b = blockIdx.x;
    const int tid = threadIdx.x;
    hbuf[tid] = hfin[(size_t)b * UU + tid];
    __syncthreads();
    float logit = -3.0e38f;
    if (tid < NC) {
        float acc = bd[tid];
        for (int u = 0; u < UU; u += 4) {
            float4 hv = *(const float4*)&hbuf[u];
            acc = fmaf(hv.x, Wd[(size_t)(u + 0) * NC + tid], acc);
            acc = fmaf(hv.y, Wd[(size_t)(u + 1) * NC + tid], acc);
            acc = fmaf(hv.z, Wd[(size_t)(u + 2) * NC + tid], acc);
            acc = fmaf(hv.w, Wd[(size_t)(u + 3) * NC + tid], acc);
        }
        logit = acc;
    }
    red[tid] = logit;
    __syncthreads();
    for (int sdx = 128; sdx > 0; sdx >>= 1) {
        if (tid < sdx) red[tid] = fmaxf(red[tid], red[tid + sdx]);
        __syncthreads();
    }
    float mx = red[0];
    __syncthreads();
    float e = (tid < NC) ? expf(logit - mx) : 0.0f;
    red[tid] = e;
    __syncthreads();
    for (int sdx = 128; sdx > 0; sdx >>= 1) {
        if (tid < sdx) red[tid] += red[tid + sdx];
        __syncthreads();
    }
    if (tid < NC) out[(size_t)b * NC + tid] = e / red[0];
}

// ---------------------------------------------------------------------------
extern "C" void kernel_launch(void* const* d_in, const int* in_sizes, int n_in,
                              void* d_out, int out_size, void* d_ws, size_t ws_size,
                              hipStream_t stream) {
    const float* x  = (const float*)d_in[0];
    const float* W  = (const float*)d_in[1];
    const float* R  = (const float*)d_in[2];
    const float* bv = (const float*)d_in[3];
    const float* Wd = (const float*)d_in[4];
    const float* bd = (const float*)d_in[5];
    float* out = (float*)d_out;

    char* ws = (char*)d_ws;
    _Float16* xph = (_Float16*)ws;                         // 16 MB
    float* zx = (float*)(ws + 16777216);                   // 64 MB
    _Float16* Wtp = (_Float16*)(ws + 83886080);            // 1 MB  (permuted W^T f16)
    _Float16* Rt  = (_Float16*)(ws + 84934656);            // 512 KB (R^T f16)
    float* hfin = (float*)(ws + 85458944);                 // 64 KB

    hipLaunchKernelGGL(pool_kernel, dim3(8192), dim3(256), 0, stream, x, xph);
    hipLaunchKernelGGL(HIP_KERNEL_NAME(transpose_cvt<1>), dim3(32, 16), dim3(256), 0,
                       stream, W, Wtp, FF, GG);
    hipLaunchKernelGGL(HIP_KERNEL_NAME(transpose_cvt<0>), dim3(32, 8), dim3(256), 0,
                       stream, R, Rt, UU, GG);
    hipLaunchKernelGGL(gemm_zx_mfma, dim3(8, 128), dim3(256), 0, stream,
                       xph, Wtp, bv, zx);
    hipLaunchKernelGGL(lstm_scan, dim3(64), dim3(512), 0, stream, zx, Rt, hfin);
    hipLaunchKernelGGL(dense_softmax, dim3(64), dim3(256), 0, stream, hfin, Wd, bd, out);
}